// Round 2
// baseline (504.760 us; speedup 1.0000x reference)
//
#include <hip/hip_runtime.h>
#include <hip/hip_cooperative_groups.h>
#include <math.h>

namespace cg = cooperative_groups;

#define NC 64          // quaternion channels
#define NB 32          // batch
#define PLANE 4096     // H*W (floats per component plane)
#define NSTAT 14
#define QBN_EPS 1e-5f
#define NBLK 512       // 2 blocks/CU on 256 CUs -- cooperative-safe
#define GROUPS_PER_BLK 4   // 2048 (b,c) plane-groups / 512 blocks

// ws layout (floats):
//   [0, 2048*14)              per-group partial sums
//   [2048*14, 2048*14+64*20)  per-channel params: A[16] + bias[4]

__global__ __launch_bounds__(256, 2) void qbn_fused(
        const float* __restrict__ x,
        const float* __restrict__ g_rr, const float* __restrict__ g_ii,
        const float* __restrict__ g_jj, const float* __restrict__ g_kk,
        const float* __restrict__ g_ri, const float* __restrict__ g_rj,
        const float* __restrict__ g_rk, const float* __restrict__ g_ij,
        const float* __restrict__ g_ik, const float* __restrict__ g_jk,
        const float* __restrict__ beta,
        float* __restrict__ ws,
        float* __restrict__ out) {
    cg::grid_group grid = cg::this_grid();

    float* __restrict__ partials = ws;                       // [2048][14]
    float* __restrict__ params   = ws + 2048 * NSTAT;        // [64][20]

    const int tid  = threadIdx.x;
    const int wave = tid >> 6;
    const int lane = tid & 63;
    const size_t comp_stride4 = (size_t)NC * PLANE / 4;      // float4 stride between components

    __shared__ float red[4][NSTAT];

    // ---------------- Phase 1: per-group partial stats ----------------
    for (int gg = 0; gg < GROUPS_PER_BLK; ++gg) {
        const int g = blockIdx.x * GROUPS_PER_BLK + gg;      // 0..2047
        const int c = g & (NC - 1);
        const int b = g >> 6;

        const float4* __restrict__ pr = (const float4*)(x + (size_t)(b * 4 * NC + c) * PLANE);
        const float4* __restrict__ pi = pr + comp_stride4;
        const float4* __restrict__ pj = pr + 2 * comp_stride4;
        const float4* __restrict__ pk = pr + 3 * comp_stride4;

        float s[NSTAT];
#pragma unroll
        for (int t = 0; t < NSTAT; ++t) s[t] = 0.0f;

#pragma unroll
        for (int it = 0; it < 4; ++it) {
            const int idx = it * 256 + tid;                  // 1024 float4 per plane
            float4 r4 = pr[idx];
            float4 i4 = pi[idx];
            float4 j4 = pj[idx];
            float4 k4 = pk[idx];
            float rv[4] = {r4.x, r4.y, r4.z, r4.w};
            float iv[4] = {i4.x, i4.y, i4.z, i4.w};
            float jv[4] = {j4.x, j4.y, j4.z, j4.w};
            float kv[4] = {k4.x, k4.y, k4.z, k4.w};
#pragma unroll
            for (int l = 0; l < 4; ++l) {
                const float r = rv[l], i = iv[l], j = jv[l], k = kv[l];
                s[0] += r;  s[1] += i;  s[2] += j;  s[3] += k;
                s[4]  = fmaf(r, r, s[4]);
                s[5]  = fmaf(i, i, s[5]);
                s[6]  = fmaf(j, j, s[6]);
                s[7]  = fmaf(k, k, s[7]);
                s[8]  = fmaf(r, i, s[8]);
                s[9]  = fmaf(r, j, s[9]);
                s[10] = fmaf(r, k, s[10]);
                s[11] = fmaf(i, j, s[11]);
                s[12] = fmaf(i, k, s[12]);
                s[13] = fmaf(j, k, s[13]);
            }
        }

        // wave reduce
#pragma unroll
        for (int t = 0; t < NSTAT; ++t) {
            float v = s[t];
#pragma unroll
            for (int off = 32; off >= 1; off >>= 1) v += __shfl_down(v, off);
            s[t] = v;
        }
        if (lane == 0) {
#pragma unroll
            for (int t = 0; t < NSTAT; ++t) red[wave][t] = s[t];
        }
        __syncthreads();
        if (tid < NSTAT) {
            partials[g * NSTAT + tid] =
                red[0][tid] + red[1][tid] + red[2][tid] + red[3][tid];
        }
        __syncthreads();   // protect red[] reuse next group
    }

    __threadfence();
    grid.sync();

    // ---------------- Phase 2: per-channel reduce + solve ----------------
    // Blocks 0..63 handle channel c = blockIdx.x; wave 0 only.
    if (blockIdx.x < NC && wave == 0) {
        const int c = blockIdx.x;
        float v[NSTAT];
        if (lane < 32) {
            const float* row = partials + (size_t)(lane * NC + c) * NSTAT;
#pragma unroll
            for (int t = 0; t < NSTAT; ++t) v[t] = row[t];
        } else {
#pragma unroll
            for (int t = 0; t < NSTAT; ++t) v[t] = 0.0f;
        }
#pragma unroll
        for (int t = 0; t < NSTAT; ++t) {
            float vv = v[t];
#pragma unroll
            for (int off = 16; off >= 1; off >>= 1) vv += __shfl_down(vv, off);
            v[t] = vv;
        }

        if (lane == 0) {
            const float inv_n = 1.0f / (float)(NB * PLANE);
            const float mr = v[0] * inv_n, mi = v[1] * inv_n;
            const float mj = v[2] * inv_n, mk = v[3] * inv_n;
            const float var_r = v[4] * inv_n - mr * mr + QBN_EPS;
            const float var_i = v[5] * inv_n - mi * mi + QBN_EPS;
            const float var_j = v[6] * inv_n - mj * mj + QBN_EPS;
            const float var_k = v[7] * inv_n - mk * mk + QBN_EPS;
            const float cov_ri = v[8]  * inv_n - mr * mi;
            const float cov_rj = v[9]  * inv_n - mr * mj;
            const float cov_rk = v[10] * inv_n - mr * mk;
            const float cov_ij = v[11] * inv_n - mi * mj;
            const float cov_ik = v[12] * inv_n - mi * mk;
            const float cov_jk = v[13] * inv_n - mj * mk;

            const float w_rr = sqrtf(var_r);
            const float w_ri = cov_ri / w_rr;
            const float w_ii = sqrtf(var_i - w_ri * w_ri);
            const float w_rj = cov_rj / w_rr;
            const float w_ij = (cov_ij - w_ri * w_rj) / w_ii;
            const float w_jj = sqrtf(var_j - (w_ij * w_ij + w_rj * w_rj));
            const float w_rk = cov_rk / w_rr;
            const float w_ik = (cov_ik - w_ri * w_rk) / w_ii;
            const float w_jk = (cov_jk - (w_ij * w_ik + w_rj * w_rk)) / w_jj;
            const float w_kk = sqrtf(var_k - (w_jk * w_jk + w_ik * w_ik + w_rk * w_rk));

            float W[4][4] = {
                {w_rr, w_ri, w_rj, w_rk},
                {0.0f, w_ii, w_ij, w_ik},
                {0.0f, 0.0f, w_jj, w_jk},
                {0.0f, 0.0f, 0.0f, w_kk},
            };
            const float grr = g_rr[c], gii = g_ii[c], gjj = g_jj[c], gkk = g_kk[c];
            const float gri = g_ri[c], grj = g_rj[c], grk = g_rk[c];
            const float gij = g_ij[c], gik = g_ik[c], gjk = g_jk[c];
            float G[4][4] = {
                {grr, gri, grj, grk},
                {gri, gii, gij, gik},
                {grj, gij, gjj, gjk},
                {grk, gik, gjk, gkk},
            };

            float A[4][4];
#pragma unroll
            for (int p = 0; p < 4; ++p)
#pragma unroll
                for (int q = 0; q < 4; ++q) {
                    float acc = 0.0f;
#pragma unroll
                    for (int t = 0; t < 4; ++t) acc = fmaf(G[p][t], W[t][q], acc);
                    A[p][q] = acc;
                }

            const float m[4] = {mr, mi, mj, mk};
            const float bb[4] = {beta[c], beta[NC + c], beta[2 * NC + c], beta[3 * NC + c]};

            float* P = params + c * 20;
#pragma unroll
            for (int p = 0; p < 4; ++p) {
#pragma unroll
                for (int q = 0; q < 4; ++q) P[p * 4 + q] = A[p][q];
                float bias = bb[p];
#pragma unroll
                for (int q = 0; q < 4; ++q) bias -= A[p][q] * m[q];
                P[16 + p] = bias;
            }
        }
    }

    __threadfence();
    grid.sync();

    // ---------------- Phase 3: apply out = A*x + b ----------------
    for (int gg = 0; gg < GROUPS_PER_BLK; ++gg) {
        const int g = blockIdx.x * GROUPS_PER_BLK + gg;
        const int c = g & (NC - 1);
        const int b = g >> 6;

        const float* __restrict__ P = params + c * 20;
        const float A00 = P[0],  A01 = P[1],  A02 = P[2],  A03 = P[3];
        const float A10 = P[4],  A11 = P[5],  A12 = P[6],  A13 = P[7];
        const float A20 = P[8],  A21 = P[9],  A22 = P[10], A23 = P[11];
        const float A30 = P[12], A31 = P[13], A32 = P[14], A33 = P[15];
        const float b0 = P[16], b1 = P[17], b2 = P[18], b3 = P[19];

        const size_t base = (size_t)(b * 4 * NC + c) * PLANE;
        const float4* __restrict__ pr = (const float4*)(x + base);
        const float4* __restrict__ pi = pr + comp_stride4;
        const float4* __restrict__ pj = pr + 2 * comp_stride4;
        const float4* __restrict__ pk = pr + 3 * comp_stride4;
        float4* __restrict__ qr = (float4*)(out + base);
        float4* __restrict__ qi = qr + comp_stride4;
        float4* __restrict__ qj = qr + 2 * comp_stride4;
        float4* __restrict__ qk = qr + 3 * comp_stride4;

#pragma unroll
        for (int it = 0; it < 4; ++it) {
            const int idx = it * 256 + tid;
            float4 r4 = pr[idx];
            float4 i4 = pi[idx];
            float4 j4 = pj[idx];
            float4 k4 = pk[idx];

            float rv[4] = {r4.x, r4.y, r4.z, r4.w};
            float iv[4] = {i4.x, i4.y, i4.z, i4.w};
            float jv[4] = {j4.x, j4.y, j4.z, j4.w};
            float kv[4] = {k4.x, k4.y, k4.z, k4.w};
            float o0[4], o1[4], o2[4], o3[4];
#pragma unroll
            for (int l = 0; l < 4; ++l) {
                const float r = rv[l], i = iv[l], j = jv[l], k = kv[l];
                o0[l] = fmaf(A00, r, fmaf(A01, i, fmaf(A02, j, fmaf(A03, k, b0))));
                o1[l] = fmaf(A10, r, fmaf(A11, i, fmaf(A12, j, fmaf(A13, k, b1))));
                o2[l] = fmaf(A20, r, fmaf(A21, i, fmaf(A22, j, fmaf(A23, k, b2))));
                o3[l] = fmaf(A30, r, fmaf(A31, i, fmaf(A32, j, fmaf(A33, k, b3))));
            }
            qr[idx] = make_float4(o0[0], o0[1], o0[2], o0[3]);
            qi[idx] = make_float4(o1[0], o1[1], o1[2], o1[3]);
            qj[idx] = make_float4(o2[0], o2[1], o2[2], o2[3]);
            qk[idx] = make_float4(o3[0], o3[1], o3[2], o3[3]);
        }
    }
}

extern "C" void kernel_launch(void* const* d_in, const int* in_sizes, int n_in,
                              void* d_out, int out_size, void* d_ws, size_t ws_size,
                              hipStream_t stream) {
    const float* x    = (const float*)d_in[0];
    const float* g_rr = (const float*)d_in[1];
    const float* g_ii = (const float*)d_in[2];
    const float* g_jj = (const float*)d_in[3];
    const float* g_kk = (const float*)d_in[4];
    const float* g_ri = (const float*)d_in[5];
    const float* g_rj = (const float*)d_in[6];
    const float* g_rk = (const float*)d_in[7];
    const float* g_ij = (const float*)d_in[8];
    const float* g_ik = (const float*)d_in[9];
    const float* g_jk = (const float*)d_in[10];
    const float* beta = (const float*)d_in[11];
    float* ws  = (float*)d_ws;
    float* out = (float*)d_out;

    void* args[] = {
        (void*)&x,
        (void*)&g_rr, (void*)&g_ii, (void*)&g_jj, (void*)&g_kk,
        (void*)&g_ri, (void*)&g_rj, (void*)&g_rk,
        (void*)&g_ij, (void*)&g_ik, (void*)&g_jk,
        (void*)&beta, (void*)&ws, (void*)&out,
    };
    hipLaunchCooperativeKernel((void*)qbn_fused, dim3(NBLK), dim3(256),
                               args, 0, stream);
}

// Round 3
// 286.545 us; speedup vs baseline: 1.7615x; 1.7615x over previous
//
#include <hip/hip_runtime.h>
#include <math.h>

#define NC 64          // quaternion channels
#define NB 32          // batch
#define PLANE 4096     // H*W (floats per component plane)
#define NSTAT 14
#define QBN_EPS 1e-5f

// ws layout (floats): [0, 2048*14) per-(b,c) partial sums
// stat order: 0..3 sum(r,i,j,k); 4..7 sum(rr,ii,jj,kk); 8..13 sum(ri,rj,rk,ij,ik,jk)

__global__ __launch_bounds__(256) void qbn_stats(const float* __restrict__ x,
                                                 float* __restrict__ partials) {
    const int g = blockIdx.x;          // 0..2047
    const int c = g & (NC - 1);
    const int b = g >> 6;
    const int tid = threadIdx.x;

    const size_t comp_stride4 = (size_t)NC * PLANE / 4;
    const float4* __restrict__ pr = (const float4*)(x + (size_t)(b * 4 * NC + c) * PLANE);
    const float4* __restrict__ pi = pr + comp_stride4;
    const float4* __restrict__ pj = pr + 2 * comp_stride4;
    const float4* __restrict__ pk = pr + 3 * comp_stride4;

    float s[NSTAT];
#pragma unroll
    for (int t = 0; t < NSTAT; ++t) s[t] = 0.0f;

#pragma unroll
    for (int it = 0; it < 4; ++it) {
        const int idx = it * 256 + tid;          // 1024 float4 per plane
        float4 r4 = pr[idx];
        float4 i4 = pi[idx];
        float4 j4 = pj[idx];
        float4 k4 = pk[idx];
        float rv[4] = {r4.x, r4.y, r4.z, r4.w};
        float iv[4] = {i4.x, i4.y, i4.z, i4.w};
        float jv[4] = {j4.x, j4.y, j4.z, j4.w};
        float kv[4] = {k4.x, k4.y, k4.z, k4.w};
#pragma unroll
        for (int l = 0; l < 4; ++l) {
            const float r = rv[l], i = iv[l], j = jv[l], k = kv[l];
            s[0] += r;  s[1] += i;  s[2] += j;  s[3] += k;
            s[4]  = fmaf(r, r, s[4]);
            s[5]  = fmaf(i, i, s[5]);
            s[6]  = fmaf(j, j, s[6]);
            s[7]  = fmaf(k, k, s[7]);
            s[8]  = fmaf(r, i, s[8]);
            s[9]  = fmaf(r, j, s[9]);
            s[10] = fmaf(r, k, s[10]);
            s[11] = fmaf(i, j, s[11]);
            s[12] = fmaf(i, k, s[12]);
            s[13] = fmaf(j, k, s[13]);
        }
    }

    // 64-lane wave reduce
#pragma unroll
    for (int t = 0; t < NSTAT; ++t) {
        float v = s[t];
#pragma unroll
        for (int off = 32; off >= 1; off >>= 1) v += __shfl_down(v, off);
        s[t] = v;
    }

    __shared__ float red[4][NSTAT];
    const int wave = tid >> 6;
    const int lane = tid & 63;
    if (lane == 0) {
#pragma unroll
        for (int t = 0; t < NSTAT; ++t) red[wave][t] = s[t];
    }
    __syncthreads();
    if (tid < NSTAT) {
        partials[g * NSTAT + tid] =
            red[0][tid] + red[1][tid] + red[2][tid] + red[3][tid];
    }
}

__global__ __launch_bounds__(256) void qbn_solve_apply(
        const float* __restrict__ x,
        const float* __restrict__ partials,
        const float* __restrict__ g_rr, const float* __restrict__ g_ii,
        const float* __restrict__ g_jj, const float* __restrict__ g_kk,
        const float* __restrict__ g_ri, const float* __restrict__ g_rj,
        const float* __restrict__ g_rk, const float* __restrict__ g_ij,
        const float* __restrict__ g_ik, const float* __restrict__ g_jk,
        const float* __restrict__ beta,
        float* __restrict__ out) {
    const int blk = blockIdx.x;
    const int c = blk & (NC - 1);
    const int b = blk >> 6;
    const int tid = threadIdx.x;

    __shared__ float P[20];   // A[16] + bias[4]

    // ---- redundant per-block solve (wave 0 only; cheap, L3-hot) ----
    if (tid < 64) {
        const int lane = tid;
        float v[NSTAT];
        if (lane < NB) {
            const float* row = partials + (size_t)(lane * NC + c) * NSTAT;
#pragma unroll
            for (int t = 0; t < NSTAT; ++t) v[t] = row[t];
        } else {
#pragma unroll
            for (int t = 0; t < NSTAT; ++t) v[t] = 0.0f;
        }
#pragma unroll
        for (int t = 0; t < NSTAT; ++t) {
            float vv = v[t];
#pragma unroll
            for (int off = 16; off >= 1; off >>= 1) vv += __shfl_down(vv, off);
            v[t] = vv;
        }

        if (lane == 0) {
            const float inv_n = 1.0f / (float)(NB * PLANE);
            const float mr = v[0] * inv_n, mi = v[1] * inv_n;
            const float mj = v[2] * inv_n, mk = v[3] * inv_n;
            const float var_r = v[4] * inv_n - mr * mr + QBN_EPS;
            const float var_i = v[5] * inv_n - mi * mi + QBN_EPS;
            const float var_j = v[6] * inv_n - mj * mj + QBN_EPS;
            const float var_k = v[7] * inv_n - mk * mk + QBN_EPS;
            const float cov_ri = v[8]  * inv_n - mr * mi;
            const float cov_rj = v[9]  * inv_n - mr * mj;
            const float cov_rk = v[10] * inv_n - mr * mk;
            const float cov_ij = v[11] * inv_n - mi * mj;
            const float cov_ik = v[12] * inv_n - mi * mk;
            const float cov_jk = v[13] * inv_n - mj * mk;

            const float w_rr = sqrtf(var_r);
            const float w_ri = cov_ri / w_rr;
            const float w_ii = sqrtf(var_i - w_ri * w_ri);
            const float w_rj = cov_rj / w_rr;
            const float w_ij = (cov_ij - w_ri * w_rj) / w_ii;
            const float w_jj = sqrtf(var_j - (w_ij * w_ij + w_rj * w_rj));
            const float w_rk = cov_rk / w_rr;
            const float w_ik = (cov_ik - w_ri * w_rk) / w_ii;
            const float w_jk = (cov_jk - (w_ij * w_ik + w_rj * w_rk)) / w_jj;
            const float w_kk = sqrtf(var_k - (w_jk * w_jk + w_ik * w_ik + w_rk * w_rk));

            float W[4][4] = {
                {w_rr, w_ri, w_rj, w_rk},
                {0.0f, w_ii, w_ij, w_ik},
                {0.0f, 0.0f, w_jj, w_jk},
                {0.0f, 0.0f, 0.0f, w_kk},
            };
            const float grr = g_rr[c], gii = g_ii[c], gjj = g_jj[c], gkk = g_kk[c];
            const float gri = g_ri[c], grj = g_rj[c], grk = g_rk[c];
            const float gij = g_ij[c], gik = g_ik[c], gjk = g_jk[c];
            float G[4][4] = {
                {grr, gri, grj, grk},
                {gri, gii, gij, gik},
                {grj, gij, gjj, gjk},
                {grk, gik, gjk, gkk},
            };

            float A[4][4];
#pragma unroll
            for (int p = 0; p < 4; ++p)
#pragma unroll
                for (int q = 0; q < 4; ++q) {
                    float acc = 0.0f;
#pragma unroll
                    for (int t = 0; t < 4; ++t) acc = fmaf(G[p][t], W[t][q], acc);
                    A[p][q] = acc;
                }

            const float m[4] = {mr, mi, mj, mk};
            const float bb[4] = {beta[c], beta[NC + c], beta[2 * NC + c], beta[3 * NC + c]};
#pragma unroll
            for (int p = 0; p < 4; ++p) {
#pragma unroll
                for (int q = 0; q < 4; ++q) P[p * 4 + q] = A[p][q];
                float bias = bb[p];
#pragma unroll
                for (int q = 0; q < 4; ++q) bias -= A[p][q] * m[q];
                P[16 + p] = bias;
            }
        }
    }
    __syncthreads();

    const float A00 = P[0],  A01 = P[1],  A02 = P[2],  A03 = P[3];
    const float A10 = P[4],  A11 = P[5],  A12 = P[6],  A13 = P[7];
    const float A20 = P[8],  A21 = P[9],  A22 = P[10], A23 = P[11];
    const float A30 = P[12], A31 = P[13], A32 = P[14], A33 = P[15];
    const float b0 = P[16], b1 = P[17], b2 = P[18], b3 = P[19];

    const size_t comp_stride4 = (size_t)NC * PLANE / 4;
    const size_t base = (size_t)(b * 4 * NC + c) * PLANE;
    const float4* __restrict__ pr = (const float4*)(x + base);
    const float4* __restrict__ pi = pr + comp_stride4;
    const float4* __restrict__ pj = pr + 2 * comp_stride4;
    const float4* __restrict__ pk = pr + 3 * comp_stride4;
    float4* __restrict__ qr = (float4*)(out + base);
    float4* __restrict__ qi = qr + comp_stride4;
    float4* __restrict__ qj = qr + 2 * comp_stride4;
    float4* __restrict__ qk = qr + 3 * comp_stride4;

#pragma unroll
    for (int it = 0; it < 4; ++it) {
        const int idx = it * 256 + tid;
        float4 r4 = pr[idx];
        float4 i4 = pi[idx];
        float4 j4 = pj[idx];
        float4 k4 = pk[idx];

        float rv[4] = {r4.x, r4.y, r4.z, r4.w};
        float iv[4] = {i4.x, i4.y, i4.z, i4.w};
        float jv[4] = {j4.x, j4.y, j4.z, j4.w};
        float kv[4] = {k4.x, k4.y, k4.z, k4.w};
        float o0[4], o1[4], o2[4], o3[4];
#pragma unroll
        for (int l = 0; l < 4; ++l) {
            const float r = rv[l], i = iv[l], j = jv[l], k = kv[l];
            o0[l] = fmaf(A00, r, fmaf(A01, i, fmaf(A02, j, fmaf(A03, k, b0))));
            o1[l] = fmaf(A10, r, fmaf(A11, i, fmaf(A12, j, fmaf(A13, k, b1))));
            o2[l] = fmaf(A20, r, fmaf(A21, i, fmaf(A22, j, fmaf(A23, k, b2))));
            o3[l] = fmaf(A30, r, fmaf(A31, i, fmaf(A32, j, fmaf(A33, k, b3))));
        }
        qr[idx] = make_float4(o0[0], o0[1], o0[2], o0[3]);
        qi[idx] = make_float4(o1[0], o1[1], o1[2], o1[3]);
        qj[idx] = make_float4(o2[0], o2[1], o2[2], o2[3]);
        qk[idx] = make_float4(o3[0], o3[1], o3[2], o3[3]);
    }
}

extern "C" void kernel_launch(void* const* d_in, const int* in_sizes, int n_in,
                              void* d_out, int out_size, void* d_ws, size_t ws_size,
                              hipStream_t stream) {
    const float* x    = (const float*)d_in[0];
    const float* g_rr = (const float*)d_in[1];
    const float* g_ii = (const float*)d_in[2];
    const float* g_jj = (const float*)d_in[3];
    const float* g_kk = (const float*)d_in[4];
    const float* g_ri = (const float*)d_in[5];
    const float* g_rj = (const float*)d_in[6];
    const float* g_rk = (const float*)d_in[7];
    const float* g_ij = (const float*)d_in[8];
    const float* g_ik = (const float*)d_in[9];
    const float* g_jk = (const float*)d_in[10];
    const float* beta = (const float*)d_in[11];
    float* partials = (float*)d_ws;     // 2048*14 floats
    float* out = (float*)d_out;

    qbn_stats<<<NB * NC, 256, 0, stream>>>(x, partials);
    qbn_solve_apply<<<NB * NC, 256, 0, stream>>>(x, partials,
                                                 g_rr, g_ii, g_jj, g_kk,
                                                 g_ri, g_rj, g_rk,
                                                 g_ij, g_ik, g_jk, beta, out);
}